// Round 20
// baseline (157.481 us; speedup 1.0000x reference)
//
#include <hip/hip_runtime.h>
#include <hip/hip_bf16.h>

typedef __attribute__((ext_vector_type(4))) float f32x4;
typedef __attribute__((ext_vector_type(8))) short bf16x8;

#define MFMA16(a, b, c) __builtin_amdgcn_mfma_f32_16x16x32_bf16(a, b, c, 0, 0, 0)

constexpr int BATCH = 4;
constexpr int SEQ   = 2048;
constexpr int DIM   = 1024;

__device__ __forceinline__ ushort f2b(float f) {
  __hip_bfloat16 h = __float2bfloat16(f);
  union { __hip_bfloat16 h; ushort u; } cv; cv.h = h; return cv.u;
}

// ---------------- fused fp32 -> bf16 convert (grid-stride) ----------------
__global__ __launch_bounds__(256) void cvt_all(
    const float* __restrict__ x, const float* __restrict__ wq,
    const float* __restrict__ wk, const float* __restrict__ wv,
    ushort* __restrict__ xb, ushort* __restrict__ wb) {
  for (int i = blockIdx.x * 256 + threadIdx.x; i < 2883584; i += 2048 * 256) {
    const float* src; ushort* dst; int off;
    if (i < 2097152) { src = x; dst = xb; off = i; }
    else {
      int j = i - 2097152;
      int s = j >> 18;
      off = j & 262143;
      src = (s == 0) ? wq : (s == 1) ? wk : wv;
      dst = wb + s * 1048576;
    }
    float4 v = reinterpret_cast<const float4*>(src)[off];
    ushort4 o;
    o.x = f2b(v.x); o.y = f2b(v.y); o.z = f2b(v.z); o.w = f2b(v.w);
    reinterpret_cast<ushort4*>(dst)[off] = o;
  }
}

__device__ __forceinline__ void gload_lds16(const void* g, void* l) {
  __builtin_amdgcn_global_load_lds(
      (const __attribute__((address_space(1))) unsigned int*)g,
      (__attribute__((address_space(3))) unsigned int*)l, 16, 0, 0);
}

#define VWAIT(n) asm volatile("s_waitcnt vmcnt(" #n ")" ::: "memory")
#define BAR() __builtin_amdgcn_s_barrier()

// ====== 256x256 8-wave GEMM, 4-phase/K-tile (round-13 proven body) ======
// MODE 0 (QK): unswapped, direct stores + bias, routed by seg=n0>>10.
// MODE 1 (S): swapped mfma, P=exp(scale*acc) ushort4 stores; per-WAVE
// 64-col partial row sums -> lpartT[b][32][2048] (coalesced; pv finishes).
template <int MODE>
__device__ __forceinline__ void gemm256_body(
    ushort* SH, int gx, int gy, int id, int bz,
    const ushort* __restrict__ Ag, const ushort* __restrict__ Bg,
    void* __restrict__ C0, void* __restrict__ C1,
    const float* __restrict__ b0, const float* __restrict__ b1,
    float* __restrict__ lpartT,
    int N, int Kd, float scale, long sA, long sB, long sC)
{
  constexpr int HSZ = 128 * 64;            // ushorts per half-buffer (16 KB)

  int nwg = gx * gy;
  int swz = (nwg & 7) ? id : ((id & 7) * (nwg >> 3) + (id >> 3));
  const int m0 = (swz / gx) * 256;
  const int n0 = (swz % gx) * 256;
  const char* Ab = (const char*)(Ag + (size_t)bz * sA);
  const char* Bb = (const char*)(Bg + (size_t)bz * sB);
  const int t = threadIdx.x;
  const int lane = t & 63;
  const int w = t >> 6;
  const int wm = w >> 2, wn = w & 3;       // 2M x 4N, wave = 128 x 64
  const size_t pA = (size_t)Kd * 2;
  const size_t pB = (size_t)Kd * 2;
  const int nt = Kd >> 6;

  auto Abuf = [&](int par, int h) { return SH + (par * 2 + h) * HSZ; };
  auto Bbuf = [&](int par, int h) { return SH + 4 * HSZ + (par * 2 + h) * HSZ; };

  auto stageH = [&](ushort* ldsb, const char* gb, size_t pitch) {
#pragma unroll
    for (int j = 0; j < 2; ++j) {
      int g = j * 512 + t;
      int r = g >> 3;
      int cb = ((g & 7) << 4) ^ ((r & 7) << 4);
      gload_lds16(gb + (size_t)r * pitch + cb,
                  (char*)ldsb + (size_t)((j * 512 + (t & ~63)) << 4));
    }
  };
  auto stA = [&](int T_, int h) {
    stageH(Abuf(T_ & 1, h), Ab + (size_t)(m0 + h * 128) * pA + (size_t)T_ * 128, pA);
  };
  auto stB = [&](int T_, int h) {
    stageH(Bbuf(T_ & 1, h), Bb + (size_t)(n0 + h * 128) * pB + (size_t)T_ * 128, pB);
  };
  auto ldfrag = [&](const ushort* base, int row, int ks) -> bf16x8 {
    int L = row * 128 + ks * 64 + ((lane >> 4) << 4);
    return *(const bf16x8*)((const char*)base + (L ^ ((row & 7) << 4)));
  };

  f32x4 acc[8][4];
#pragma unroll
  for (int i = 0; i < 8; ++i)
#pragma unroll
    for (int j = 0; j < 4; ++j) acc[i][j] = 0.f;

  bf16x8 a0[4][2], a1[4][2];
  bf16x8 b[2][2];

#define LDA0(Ac)                                                         \
  _Pragma("unroll") for (int mi = 0; mi < 4; ++mi) {                     \
    int r = mi * 16 + (lane & 15);                                       \
    a0[mi][0] = ldfrag(Ac, r, 0); a0[mi][1] = ldfrag(Ac, r, 1);          \
  }
#define LDA1(Ac)                                                         \
  _Pragma("unroll") for (int mi = 0; mi < 4; ++mi) {                     \
    int r = 64 + mi * 16 + (lane & 15);                                  \
    a1[mi][0] = ldfrag(Ac, r, 0); a1[mi][1] = ldfrag(Ac, r, 1);          \
  }
#define LDB(Bc, sub)                                                     \
  _Pragma("unroll") for (int ni = 0; ni < 2; ++ni) {                     \
    int r = (wn & 1) * 64 + ((sub) * 2 + ni) * 16 + (lane & 15);         \
    b[ni][0] = ldfrag(Bc, r, 0); b[ni][1] = ldfrag(Bc, r, 1);            \
  }
#define MF(AV, MB, NB)                                                   \
  __builtin_amdgcn_s_setprio(1);                                         \
  _Pragma("unroll") for (int mi = 0; mi < 4; ++mi)                       \
      _Pragma("unroll") for (int ni = 0; ni < 2; ++ni) {                 \
    if constexpr (MODE == 1) {                                           \
      acc[(MB) + mi][(NB) + ni] =                                        \
          MFMA16(b[ni][0], AV[mi][0], acc[(MB) + mi][(NB) + ni]);        \
      acc[(MB) + mi][(NB) + ni] =                                        \
          MFMA16(b[ni][1], AV[mi][1], acc[(MB) + mi][(NB) + ni]);        \
    } else {                                                             \
      acc[(MB) + mi][(NB) + ni] =                                        \
          MFMA16(AV[mi][0], b[ni][0], acc[(MB) + mi][(NB) + ni]);        \
      acc[(MB) + mi][(NB) + ni] =                                        \
          MFMA16(AV[mi][1], b[ni][1], acc[(MB) + mi][(NB) + ni]);        \
    }                                                                    \
  }                                                                      \
  __builtin_amdgcn_s_setprio(0);

  stA(0, 0); stA(0, 1); stB(0, 0); stB(0, 1); stA(1, 0); stA(1, 1);
  VWAIT(4);
  BAR();

  for (int tt = 0; tt < nt; ++tt) {
    const ushort* Ac = Abuf(tt & 1, wm);
    const ushort* Bc = Bbuf(tt & 1, wn >> 1);
    LDA0(Ac); LDB(Bc, 0);
    if (tt + 1 < nt) stB(tt + 1, 0);
    BAR();
    MF(a0, 0, 0);
    BAR();
    LDA1(Ac);
    if (tt + 1 < nt) stB(tt + 1, 1);
    BAR();
    MF(a1, 4, 0);
    BAR();
    LDB(Bc, 1);
    if (tt + 2 < nt) stA(tt + 2, 0);
    BAR();
    MF(a1, 4, 2);
    BAR();
    if (tt + 2 < nt) { stA(tt + 2, 1); VWAIT(4); }
    else VWAIT(0);
    BAR();
    MF(a0, 0, 2);
    BAR();
  }
#undef LDA0
#undef LDA1
#undef LDB
#undef MF

  if constexpr (MODE == 0) {
    const int seg = n0 >> 10;
    const int n0l = n0 & 1023;
    const float* biasp = seg == 0 ? b0 : b1;
    ushort* Ch = (ushort*)(seg == 0 ? C0 : C1);
#pragma unroll
    for (int mf = 0; mf < 8; ++mf)
#pragma unroll
      for (int nf = 0; nf < 4; ++nf) {
        int gn = n0l + wn * 64 + nf * 16 + (lane & 15);
        float bb = biasp[gn];
#pragma unroll
        for (int r = 0; r < 4; ++r) {
          int gm = m0 + wm * 128 + mf * 16 + (lane >> 4) * 4 + r;
          Ch[(size_t)gm * N + gn] = f2b(acc[mf][nf][r] * scale + bb);
        }
      }
  } else {
    // S (swapped): P stores + per-wave 64-col partials -> lpartT[b][32][2048]
    ushort* Ch = (ushort*)C0 + (size_t)bz * sC;
    const int j32 = (n0 >> 8) * 4 + wn;    // 0..31
    float* lrow = lpartT + ((size_t)bz * 32 + j32) * SEQ + m0 + wm * 128;
#pragma unroll
    for (int mf = 0; mf < 8; ++mf) {
      int gm = m0 + wm * 128 + mf * 16 + (lane & 15);
      float rs = 0.f;
#pragma unroll
      for (int nf = 0; nf < 4; ++nf) {
        int gn0 = n0 + wn * 64 + nf * 16 + (lane >> 4) * 4;
        float e0 = __expf(acc[mf][nf][0] * scale);
        float e1 = __expf(acc[mf][nf][1] * scale);
        float e2 = __expf(acc[mf][nf][2] * scale);
        float e3 = __expf(acc[mf][nf][3] * scale);
        rs += (e0 + e1) + (e2 + e3);
        ushort4 pk;
        pk.x = f2b(e0); pk.y = f2b(e1); pk.z = f2b(e2); pk.w = f2b(e3);
        *(ushort4*)&Ch[(size_t)gm * N + gn0] = pk;
      }
      rs += __shfl_xor(rs, 16);
      rs += __shfl_xor(rs, 32);
      if (lane < 16) lrow[mf * 16 + lane] = rs;   // coalesced 64B run
    }
  }
}

// ====== V body: 128x256 8-wave triple-buffered (round-13 proven) ======
__device__ __forceinline__ void gemm_v_body(
    ushort* SH, int gx, int gy, int id,
    const ushort* __restrict__ Ag, const ushort* __restrict__ Bg,
    void* __restrict__ C0, const float* __restrict__ x0)
{
  constexpr int ASZ = 128 * 64;
  constexpr int BSZ = 256 * 64;
  constexpr int N = DIM, Kd = DIM;

  int nwg = gx * gy;
  int swz = (nwg & 7) ? id : ((id & 7) * (nwg >> 3) + (id >> 3));
  const int m0 = (swz / gx) * 128;
  const int n0 = (swz % gx) * 256;
  const char* Ab = (const char*)Ag;
  const char* Bb = (const char*)Bg;
  const int t = threadIdx.x;
  const int lane = t & 63;
  const int w = t >> 6;
  const int wm = w >> 2, wn = w & 3;
  const size_t pA = (size_t)Kd * 2;
  const size_t pB = (size_t)Kd * 2;
  const int nt = Kd >> 6;

  auto stageH = [&](ushort* ldsb, const char* gb, size_t pitch) {
#pragma unroll
    for (int j = 0; j < 2; ++j) {
      int g = j * 512 + t;
      int r = g >> 3;
      int cb = ((g & 7) << 4) ^ ((r & 7) << 4);
      gload_lds16(gb + (size_t)r * pitch + cb,
                  (char*)ldsb + (size_t)((j * 512 + (t & ~63)) << 4));
    }
  };
  auto ldfrag = [&](const ushort* base, int row, int ks) -> bf16x8 {
    int L = row * 128 + ks * 64 + ((lane >> 4) << 4);
    return *(const bf16x8*)((const char*)base + (L ^ ((row & 7) << 4)));
  };
  auto stageT = [&](int tile) {
    ushort* Abuf = SH + (tile % 3) * ASZ;
    ushort* Bbuf = SH + 3 * ASZ + (tile % 3) * BSZ;
    const size_t ko = (size_t)tile * 128;
    stageH(Abuf, Ab + (size_t)m0 * pA + ko, pA);
    stageH(Bbuf, Bb + (size_t)n0 * pB + ko, pB);
    stageH(Bbuf + 128 * 64, Bb + (size_t)(n0 + 128) * pB + ko, pB);
  };

  f32x4 acc[4][4];
#pragma unroll
  for (int i = 0; i < 4; ++i)
#pragma unroll
    for (int j = 0; j < 4; ++j) acc[i][j] = 0.f;

  bf16x8 a[2][2];
  bf16x8 b[4][2];

  stageT(0);
  stageT(1);

  for (int tt = 0; tt < nt; ++tt) {
    const ushort* Ac = SH + (tt % 3) * ASZ;
    const ushort* Bc = SH + 3 * ASZ + (tt % 3) * BSZ;
    BAR();
    if (tt + 2 < nt) { stageT(tt + 2); VWAIT(12); }
    else if (tt + 1 < nt) VWAIT(6);
    else VWAIT(0);
    BAR();
#pragma unroll
    for (int nf = 0; nf < 4; ++nf) {
      int r = wn * 64 + nf * 16 + (lane & 15);
      b[nf][0] = ldfrag(Bc, r, 0);
      b[nf][1] = ldfrag(Bc, r, 1);
    }
#pragma unroll
    for (int g = 0; g < 2; ++g) {
#pragma unroll
      for (int i = 0; i < 2; ++i) {
        int r = wm * 64 + (g * 2 + i) * 16 + (lane & 15);
        a[i][0] = ldfrag(Ac, r, 0);
        a[i][1] = ldfrag(Ac, r, 1);
      }
      __builtin_amdgcn_s_setprio(1);
#pragma unroll
      for (int i = 0; i < 2; ++i)
#pragma unroll
        for (int nf = 0; nf < 4; ++nf) {
          acc[g * 2 + i][nf] = MFMA16(a[i][0], b[nf][0], acc[g * 2 + i][nf]);
          acc[g * 2 + i][nf] = MFMA16(a[i][1], b[nf][1], acc[g * 2 + i][nf]);
        }
      __builtin_amdgcn_s_setprio(0);
    }
  }

  // V epilogue: write transposed to vt[b][d][token] via LDS bounce.
  __syncthreads();
  const int b_ = m0 >> 11;
  const int tok0 = m0 & 2047;
  ushort* vtb = (ushort*)C0 + (size_t)b_ * DIM * SEQ;
  ushort* T = SH;                        // [256 d][132 tok]
  {
#pragma unroll
    for (int nf = 0; nf < 4; ++nf) {
      int d_loc = wn * 64 + nf * 16 + (lane & 15);
      float bvv = x0[n0 + d_loc];
#pragma unroll
      for (int mf = 0; mf < 4; ++mf) {
        int tok = wm * 64 + mf * 16 + (lane >> 4) * 4;
        ushort4 pk;
        pk.x = f2b(acc[mf][nf][0] + bvv);
        pk.y = f2b(acc[mf][nf][1] + bvv);
        pk.z = f2b(acc[mf][nf][2] + bvv);
        pk.w = f2b(acc[mf][nf][3] + bvv);
        *(ushort4*)&T[d_loc * 132 + tok] = pk;
      }
    }
  }
  __syncthreads();
  {
    int rr = t >> 1, ch = t & 1;
    ushort* dst = vtb + (size_t)(n0 + rr) * SEQ + tok0 + ch * 64;
#pragma unroll
    for (int i = 0; i < 8; ++i)
      *(bf16x8*)(dst + i * 8) = *(const bf16x8*)&T[rr * 132 + ch * 64 + i * 8];
  }
}

// ====== FUSED qk + v: 512 blocks; v blocks backfill CUs as qk retires ======
__global__ __launch_bounds__(512) void qkv_fused(
    const ushort* __restrict__ xb, const ushort* __restrict__ wqk,
    void* __restrict__ qb, void* __restrict__ kb,
    const float* __restrict__ bq, const float* __restrict__ bk,
    const ushort* __restrict__ wv, void* __restrict__ vt,
    const float* __restrict__ bv)
{
  __shared__ ushort SH[73728];   // 144 KiB (max of both bodies)
  if (blockIdx.x < 256) {
    gemm256_body<0>(SH, 8, 32, blockIdx.x, 0, xb, wqk, qb, kb, bq, bk,
                    nullptr, DIM, DIM, 1.0f, 0, 0, 0);
  } else {
    gemm_v_body(SH, 4, 64, blockIdx.x - 256, xb, wv, vt, bv);
  }
}

__global__ __launch_bounds__(512) void gemm_s(
    const ushort* __restrict__ Ag, const ushort* __restrict__ Bg,
    void* __restrict__ C0, float* __restrict__ lpartT) {
  __shared__ ushort SH[65536];   // 128 KiB
  gemm256_body<1>(SH, 8, 8, blockIdx.y * 8 + blockIdx.x, blockIdx.z,
                  Ag, Bg, C0, nullptr, nullptr, nullptr, lpartT,
                  SEQ, DIM, 0.03125f, (long)SEQ * DIM, (long)SEQ * DIM,
                  (long)SEQ * SEQ);
}

// ====== PV: 128x128, BK=64, 256 thr (4 waves 2Mx2N), 2 BLOCKS/CU ======
// Round-15 body; rowsum HOISTED to prologue: the 32 L2-hot lpartT loads
// issue right after stageT(0) and drain with tile-0's counted VWAIT
// (per-wave vmcnt trace verified for both branch classes; wave-uniform).
// Epilogue then needs no barrier and no extra loads.
__global__ __launch_bounds__(256) void gemm_pv(
    const ushort* __restrict__ Ag, const ushort* __restrict__ Bg,
    void* __restrict__ C0, const float* __restrict__ lpartT)
{
  constexpr int TSZ = 128 * 64;
  __shared__ ushort SH[4 * TSZ];           // 64 KiB
  __shared__ float Lf2[128];
  constexpr int N = DIM, Kd = SEQ;

  int nwg = gridDim.x * gridDim.y;
  int id = blockIdx.y * gridDim.x + blockIdx.x;
  int swz = (nwg & 7) ? id : ((id & 7) * (nwg >> 3) + (id >> 3));
  const int m0 = (swz / gridDim.x) * 128;
  const int n0 = (swz % gridDim.x) * 128;
  const int bz = blockIdx.z;
  const char* Ab = (const char*)(Ag + (size_t)bz * (size_t)SEQ * SEQ);
  const char* Bb = (const char*)(Bg + (size_t)bz * (size_t)DIM * SEQ);
  const int t = threadIdx.x;
  const int lane = t & 63;
  const int w = t >> 6;
  const int wm = w >> 1, wn = w & 1;
  const size_t pitch = (size_t)Kd * 2;
  const int nt = Kd >> 6;

  auto stage1 = [&](ushort* ldsb, const char* gb) {
#pragma unroll
    for (int j = 0; j < 4; ++j) {
      int g = j * 256 + t;
      int r = g >> 3;
      int cb = ((g & 7) << 4) ^ ((r & 7) << 4);
      gload_lds16(gb + (size_t)r * pitch + cb,
                  (char*)ldsb + (size_t)((j * 256 + (t & ~63)) << 4));
    }
  };
  auto stageT = [&](int tile) {
    const size_t ko = (size_t)tile * 128;
    stage1(SH + (tile & 1) * TSZ, Ab + (size_t)m0 * pitch + ko);
    stage1(SH + 2 * TSZ + (tile & 1) * TSZ, Bb + (size_t)n0 * pitch + ko);
  };
  auto ldfrag = [&](const ushort* base, int row, int ks) -> bf16x8 {
    int L = row * 128 + ks * 64 + ((lane >> 4) << 4);
    return *(const bf16x8*)((const char*)base + (L ^ ((row & 7) << 4)));
  };

  f32x4 acc[4][4];
#pragma unroll
  for (int i = 0; i < 4; ++i)
#pragma unroll
    for (int j = 0; j < 4; ++j) acc[i][j] = 0.f;

  bf16x8 a[2][2];
  bf16x8 b[4][2];

  stageT(0);
  // hoisted rowsum: drains with tile-0's VWAIT; waves 0,1 take uniformly
  if (t < 128) {
    const float* lp = lpartT + (size_t)bz * 32 * SEQ + m0 + t;
    float s = 0.f;
#pragma unroll
    for (int j = 0; j < 32; ++j) s += lp[(size_t)j * SEQ];
    Lf2[t] = 1.f / s;
  }

  for (int tt = 0; tt < nt; ++tt) {
    const ushort* Ac = SH + (tt & 1) * TSZ;
    const ushort* Bc = SH + 2 * TSZ + (tt & 1) * TSZ;
    BAR();
    if (tt + 1 < nt) { stageT(tt + 1); VWAIT(8); }
    else VWAIT(0);
    BAR();
#pragma unroll
    for (int nf = 0; nf < 4; ++nf) {
      int r = wn * 64 + nf * 16 + (lane & 15);
      b[nf][0] = ldfrag(Bc, r, 0);
      b[nf][1] = ldfrag(Bc, r, 1);
    }
#pragma unroll
    for (int g = 0; g < 2; ++g) {
#pragma unroll
      for (int i = 0; i < 2; ++i) {
        int r = wm * 64 + (g * 2 + i) * 16 + (lane & 15);
        a[i][0] = ldfrag(Ac, r, 0);
        a[i][1] = ldfrag(Ac, r, 1);
      }
      __builtin_amdgcn_s_setprio(1);
#pragma unroll
      for (int i = 0; i < 2; ++i)
#pragma unroll
        for (int nf = 0; nf < 4; ++nf) {
          acc[g * 2 + i][nf] = MFMA16(b[nf][0], a[i][0], acc[g * 2 + i][nf]);
          acc[g * 2 + i][nf] = MFMA16(b[nf][1], a[i][1], acc[g * 2 + i][nf]);
        }
      __builtin_amdgcn_s_setprio(0);
    }
  }

  // epilogue: Lf2 ordered by the loop's barriers (write long-retired)
  float* Cf = (float*)C0 + (size_t)bz * (size_t)SEQ * DIM;
#pragma unroll
  for (int mf = 0; mf < 4; ++mf) {
    int rloc = wm * 64 + mf * 16 + (lane & 15);
    int row = m0 + rloc;
    float inv = Lf2[rloc];
#pragma unroll
    for (int nf = 0; nf < 4; ++nf) {
      int gn0 = n0 + wn * 64 + nf * 16 + (lane >> 4) * 4;
      f32x4 o = acc[mf][nf] * inv;
      *(f32x4*)&Cf[(size_t)row * DIM + gn0] = o;
    }
  }
}

// ---------------- launcher ----------------
extern "C" void kernel_launch(void* const* d_in, const int* in_sizes, int n_in,
                              void* d_out, int out_size, void* d_ws, size_t ws_size,
                              hipStream_t stream) {
  const float* x  = (const float*)d_in[0];
  const float* Wq = (const float*)d_in[1];
  const float* bq = (const float*)d_in[2];
  const float* Wk = (const float*)d_in[3];
  const float* bk = (const float*)d_in[4];
  const float* Wv = (const float*)d_in[5];
  const float* bv = (const float*)d_in[6];
  float* out = (float*)d_out;

  char* ws = (char*)d_ws;
  // ws layout (bytes), total 90.2 MB:
  //   [0, 32M)      SP  [4][2048][2048] bf16 (xb at [16M,32M) dead by then)
  //   [32M, 38.3M)  wb  (dead after qkv_fused) / lpartT overlay [4][32][2048] f32
  //   [38.3M, ...)  qb | kb | vt  (16M each)
  ushort* xb = (ushort*)(ws + 16777216);
  ushort* wb = (ushort*)(ws + 33554432);
  ushort* qb = (ushort*)(ws + 39845888);
  ushort* kb = (ushort*)(ws + 56623104);
  ushort* vt = (ushort*)(ws + 73400320);
  ushort* SP = (ushort*)(ws);
  float* lpartT = (float*)(ws + 33554432);  // [4][32][2048] f32 = 1 MB

  cvt_all<<<2048, 256, 0, stream>>>(x, Wq, Wk, Wv, xb, wb);
  // Fused: blocks 0-255 = Q,K projection (256x256 tiles);
  //        blocks 256-511 = V projection (128x256 tiles, transposed out).
  qkv_fused<<<512, 512, 0, stream>>>(xb, wb, qb, kb, bq, bk,
                                     wb + 2097152, vt, bv);
  // P = exp(Q K^T / 32) -> SP (+ wave partial sums -> lpartT).  256 blocks.
  gemm_s<<<dim3(8, 8, 4), 512, 0, stream>>>(qb, kb, SP, lpartT);
  // O = (P V) / rowsum.  512 blocks (8x16x4) of 128x128 -> 2 blocks/CU.
  gemm_pv<<<dim3(8, 16, 4), 256, 0, stream>>>(SP, vt, out, lpartT);
}

// Round 21
// 154.534 us; speedup vs baseline: 1.0191x; 1.0191x over previous
//
#include <hip/hip_runtime.h>
#include <hip/hip_bf16.h>

typedef __attribute__((ext_vector_type(4))) float f32x4;
typedef __attribute__((ext_vector_type(8))) short bf16x8;

#define MFMA16(a, b, c) __builtin_amdgcn_mfma_f32_16x16x32_bf16(a, b, c, 0, 0, 0)

constexpr int BATCH = 4;
constexpr int SEQ   = 2048;
constexpr int DIM   = 1024;

__device__ __forceinline__ ushort f2b(float f) {
  __hip_bfloat16 h = __float2bfloat16(f);
  union { __hip_bfloat16 h; ushort u; } cv; cv.h = h; return cv.u;
}

// ---------------- fused fp32 -> bf16 convert ----------------
__global__ __launch_bounds__(256) void cvt_all(
    const float* __restrict__ x, const float* __restrict__ wq,
    const float* __restrict__ wk, const float* __restrict__ wv,
    ushort* __restrict__ xb, ushort* __restrict__ wb) {
  int i = blockIdx.x * 256 + threadIdx.x;
  const float* src; ushort* dst; int off;
  if (i < 2097152) { src = x; dst = xb; off = i; }
  else {
    int j = i - 2097152;
    int s = j >> 18;
    off = j & 262143;
    src = (s == 0) ? wq : (s == 1) ? wk : wv;
    dst = wb + s * 1048576;
  }
  float4 v = reinterpret_cast<const float4*>(src)[off];
  ushort4 o;
  o.x = f2b(v.x); o.y = f2b(v.y); o.z = f2b(v.z); o.w = f2b(v.w);
  reinterpret_cast<ushort4*>(dst)[off] = o;
}

__device__ __forceinline__ void gload_lds16(const void* g, void* l) {
  __builtin_amdgcn_global_load_lds(
      (const __attribute__((address_space(1))) unsigned int*)g,
      (__attribute__((address_space(3))) unsigned int*)l, 16, 0, 0);
}

#define VWAIT(n) asm volatile("s_waitcnt vmcnt(" #n ")" ::: "memory")
#define BAR() __builtin_amdgcn_s_barrier()

// ====== 256x256 8-wave GEMM, 4-phase/K-tile (round-13 proven body) ======
// MODE 0 (QK): unswapped, direct stores + bias, routed by seg=n0>>10.
// MODE 1 (S): swapped mfma, P=exp(scale*acc) ushort4 stores; per-WAVE
// 64-col partial row sums written straight to lpartT[b][32][2048]
// (coalesced 64B runs; no LDS reduce, no extra barriers — pv finishes it).
template <int MODE>
__device__ __forceinline__ void gemm256_body(
    ushort* SH, int gx, int gy, int id, int bz,
    const ushort* __restrict__ Ag, const ushort* __restrict__ Bg,
    void* __restrict__ C0, void* __restrict__ C1,
    const float* __restrict__ b0, const float* __restrict__ b1,
    float* __restrict__ lpartT,
    int N, int Kd, float scale, long sA, long sB, long sC)
{
  constexpr int HSZ = 128 * 64;            // ushorts per half-buffer (16 KB)

  int nwg = gx * gy;
  int swz = (nwg & 7) ? id : ((id & 7) * (nwg >> 3) + (id >> 3));
  const int m0 = (swz / gx) * 256;
  const int n0 = (swz % gx) * 256;
  const char* Ab = (const char*)(Ag + (size_t)bz * sA);
  const char* Bb = (const char*)(Bg + (size_t)bz * sB);
  const int t = threadIdx.x;
  const int lane = t & 63;
  const int w = t >> 6;
  const int wm = w >> 2, wn = w & 3;       // 2M x 4N, wave = 128 x 64
  const size_t pA = (size_t)Kd * 2;
  const size_t pB = (size_t)Kd * 2;
  const int nt = Kd >> 6;

  auto Abuf = [&](int par, int h) { return SH + (par * 2 + h) * HSZ; };
  auto Bbuf = [&](int par, int h) { return SH + 4 * HSZ + (par * 2 + h) * HSZ; };

  auto stageH = [&](ushort* ldsb, const char* gb, size_t pitch) {
#pragma unroll
    for (int j = 0; j < 2; ++j) {
      int g = j * 512 + t;
      int r = g >> 3;
      int cb = ((g & 7) << 4) ^ ((r & 7) << 4);
      gload_lds16(gb + (size_t)r * pitch + cb,
                  (char*)ldsb + (size_t)((j * 512 + (t & ~63)) << 4));
    }
  };
  auto stA = [&](int T_, int h) {
    stageH(Abuf(T_ & 1, h), Ab + (size_t)(m0 + h * 128) * pA + (size_t)T_ * 128, pA);
  };
  auto stB = [&](int T_, int h) {
    stageH(Bbuf(T_ & 1, h), Bb + (size_t)(n0 + h * 128) * pB + (size_t)T_ * 128, pB);
  };
  auto ldfrag = [&](const ushort* base, int row, int ks) -> bf16x8 {
    int L = row * 128 + ks * 64 + ((lane >> 4) << 4);
    return *(const bf16x8*)((const char*)base + (L ^ ((row & 7) << 4)));
  };

  f32x4 acc[8][4];
#pragma unroll
  for (int i = 0; i < 8; ++i)
#pragma unroll
    for (int j = 0; j < 4; ++j) acc[i][j] = 0.f;

  bf16x8 a0[4][2], a1[4][2];
  bf16x8 b[2][2];

#define LDA0(Ac)                                                         \
  _Pragma("unroll") for (int mi = 0; mi < 4; ++mi) {                     \
    int r = mi * 16 + (lane & 15);                                       \
    a0[mi][0] = ldfrag(Ac, r, 0); a0[mi][1] = ldfrag(Ac, r, 1);          \
  }
#define LDA1(Ac)                                                         \
  _Pragma("unroll") for (int mi = 0; mi < 4; ++mi) {                     \
    int r = 64 + mi * 16 + (lane & 15);                                  \
    a1[mi][0] = ldfrag(Ac, r, 0); a1[mi][1] = ldfrag(Ac, r, 1);          \
  }
#define LDB(Bc, sub)                                                     \
  _Pragma("unroll") for (int ni = 0; ni < 2; ++ni) {                     \
    int r = (wn & 1) * 64 + ((sub) * 2 + ni) * 16 + (lane & 15);         \
    b[ni][0] = ldfrag(Bc, r, 0); b[ni][1] = ldfrag(Bc, r, 1);            \
  }
#define MF(AV, MB, NB)                                                   \
  __builtin_amdgcn_s_setprio(1);                                         \
  _Pragma("unroll") for (int mi = 0; mi < 4; ++mi)                       \
      _Pragma("unroll") for (int ni = 0; ni < 2; ++ni) {                 \
    if constexpr (MODE == 1) {                                           \
      acc[(MB) + mi][(NB) + ni] =                                        \
          MFMA16(b[ni][0], AV[mi][0], acc[(MB) + mi][(NB) + ni]);        \
      acc[(MB) + mi][(NB) + ni] =                                        \
          MFMA16(b[ni][1], AV[mi][1], acc[(MB) + mi][(NB) + ni]);        \
    } else {                                                             \
      acc[(MB) + mi][(NB) + ni] =                                        \
          MFMA16(AV[mi][0], b[ni][0], acc[(MB) + mi][(NB) + ni]);        \
      acc[(MB) + mi][(NB) + ni] =                                        \
          MFMA16(AV[mi][1], b[ni][1], acc[(MB) + mi][(NB) + ni]);        \
    }                                                                    \
  }                                                                      \
  __builtin_amdgcn_s_setprio(0);

  stA(0, 0); stA(0, 1); stB(0, 0); stB(0, 1); stA(1, 0); stA(1, 1);
  VWAIT(4);
  BAR();

  for (int tt = 0; tt < nt; ++tt) {
    const ushort* Ac = Abuf(tt & 1, wm);
    const ushort* Bc = Bbuf(tt & 1, wn >> 1);
    LDA0(Ac); LDB(Bc, 0);
    if (tt + 1 < nt) stB(tt + 1, 0);
    BAR();
    MF(a0, 0, 0);
    BAR();
    LDA1(Ac);
    if (tt + 1 < nt) stB(tt + 1, 1);
    BAR();
    MF(a1, 4, 0);
    BAR();
    LDB(Bc, 1);
    if (tt + 2 < nt) stA(tt + 2, 0);
    BAR();
    MF(a1, 4, 2);
    BAR();
    if (tt + 2 < nt) { stA(tt + 2, 1); VWAIT(4); }
    else VWAIT(0);
    BAR();
    MF(a0, 0, 2);
    BAR();
  }
#undef LDA0
#undef LDA1
#undef LDB
#undef MF

  if constexpr (MODE == 0) {
    const int seg = n0 >> 10;
    const int n0l = n0 & 1023;
    const float* biasp = seg == 0 ? b0 : b1;
    ushort* Ch = (ushort*)(seg == 0 ? C0 : C1);
#pragma unroll
    for (int mf = 0; mf < 8; ++mf)
#pragma unroll
      for (int nf = 0; nf < 4; ++nf) {
        int gn = n0l + wn * 64 + nf * 16 + (lane & 15);
        float bb = biasp[gn];
#pragma unroll
        for (int r = 0; r < 4; ++r) {
          int gm = m0 + wm * 128 + mf * 16 + (lane >> 4) * 4 + r;
          Ch[(size_t)gm * N + gn] = f2b(acc[mf][nf][r] * scale + bb);
        }
      }
  } else {
    // S (swapped): P stores + per-wave 64-col partials -> lpartT[b][32][2048]
    ushort* Ch = (ushort*)C0 + (size_t)bz * sC;
    const int j32 = (n0 >> 8) * 4 + wn;    // 0..31
    float* lrow = lpartT + ((size_t)bz * 32 + j32) * SEQ + m0 + wm * 128;
#pragma unroll
    for (int mf = 0; mf < 8; ++mf) {
      int gm = m0 + wm * 128 + mf * 16 + (lane & 15);
      float rs = 0.f;
#pragma unroll
      for (int nf = 0; nf < 4; ++nf) {
        int gn0 = n0 + wn * 64 + nf * 16 + (lane >> 4) * 4;
        float e0 = __expf(acc[mf][nf][0] * scale);
        float e1 = __expf(acc[mf][nf][1] * scale);
        float e2 = __expf(acc[mf][nf][2] * scale);
        float e3 = __expf(acc[mf][nf][3] * scale);
        rs += (e0 + e1) + (e2 + e3);
        ushort4 pk;
        pk.x = f2b(e0); pk.y = f2b(e1); pk.z = f2b(e2); pk.w = f2b(e3);
        *(ushort4*)&Ch[(size_t)gm * N + gn0] = pk;
      }
      rs += __shfl_xor(rs, 16);
      rs += __shfl_xor(rs, 32);
      if (lane < 16) lrow[mf * 16 + lane] = rs;   // coalesced 64B run
    }
  }
}

// ====== V body: 128x256 8-wave triple-buffered (round-13 proven) ======
__device__ __forceinline__ void gemm_v_body(
    ushort* SH, int gx, int gy, int id,
    const ushort* __restrict__ Ag, const ushort* __restrict__ Bg,
    void* __restrict__ C0, const float* __restrict__ x0)
{
  constexpr int ASZ = 128 * 64;
  constexpr int BSZ = 256 * 64;
  constexpr int N = DIM, Kd = DIM;

  int nwg = gx * gy;
  int swz = (nwg & 7) ? id : ((id & 7) * (nwg >> 3) + (id >> 3));
  const int m0 = (swz / gx) * 128;
  const int n0 = (swz % gx) * 256;
  const char* Ab = (const char*)Ag;
  const char* Bb = (const char*)Bg;
  const int t = threadIdx.x;
  const int lane = t & 63;
  const int w = t >> 6;
  const int wm = w >> 2, wn = w & 3;
  const size_t pA = (size_t)Kd * 2;
  const size_t pB = (size_t)Kd * 2;
  const int nt = Kd >> 6;

  auto stageH = [&](ushort* ldsb, const char* gb, size_t pitch) {
#pragma unroll
    for (int j = 0; j < 2; ++j) {
      int g = j * 512 + t;
      int r = g >> 3;
      int cb = ((g & 7) << 4) ^ ((r & 7) << 4);
      gload_lds16(gb + (size_t)r * pitch + cb,
                  (char*)ldsb + (size_t)((j * 512 + (t & ~63)) << 4));
    }
  };
  auto ldfrag = [&](const ushort* base, int row, int ks) -> bf16x8 {
    int L = row * 128 + ks * 64 + ((lane >> 4) << 4);
    return *(const bf16x8*)((const char*)base + (L ^ ((row & 7) << 4)));
  };
  auto stageT = [&](int tile) {
    ushort* Abuf = SH + (tile % 3) * ASZ;
    ushort* Bbuf = SH + 3 * ASZ + (tile % 3) * BSZ;
    const size_t ko = (size_t)tile * 128;
    stageH(Abuf, Ab + (size_t)m0 * pA + ko, pA);
    stageH(Bbuf, Bb + (size_t)n0 * pB + ko, pB);
    stageH(Bbuf + 128 * 64, Bb + (size_t)(n0 + 128) * pB + ko, pB);
  };

  f32x4 acc[4][4];
#pragma unroll
  for (int i = 0; i < 4; ++i)
#pragma unroll
    for (int j = 0; j < 4; ++j) acc[i][j] = 0.f;

  bf16x8 a[2][2];
  bf16x8 b[4][2];

  stageT(0);
  stageT(1);

  for (int tt = 0; tt < nt; ++tt) {
    const ushort* Ac = SH + (tt % 3) * ASZ;
    const ushort* Bc = SH + 3 * ASZ + (tt % 3) * BSZ;
    BAR();
    if (tt + 2 < nt) { stageT(tt + 2); VWAIT(12); }
    else if (tt + 1 < nt) VWAIT(6);
    else VWAIT(0);
    BAR();
#pragma unroll
    for (int nf = 0; nf < 4; ++nf) {
      int r = wn * 64 + nf * 16 + (lane & 15);
      b[nf][0] = ldfrag(Bc, r, 0);
      b[nf][1] = ldfrag(Bc, r, 1);
    }
#pragma unroll
    for (int g = 0; g < 2; ++g) {
#pragma unroll
      for (int i = 0; i < 2; ++i) {
        int r = wm * 64 + (g * 2 + i) * 16 + (lane & 15);
        a[i][0] = ldfrag(Ac, r, 0);
        a[i][1] = ldfrag(Ac, r, 1);
      }
      __builtin_amdgcn_s_setprio(1);
#pragma unroll
      for (int i = 0; i < 2; ++i)
#pragma unroll
        for (int nf = 0; nf < 4; ++nf) {
          acc[g * 2 + i][nf] = MFMA16(a[i][0], b[nf][0], acc[g * 2 + i][nf]);
          acc[g * 2 + i][nf] = MFMA16(a[i][1], b[nf][1], acc[g * 2 + i][nf]);
        }
      __builtin_amdgcn_s_setprio(0);
    }
  }

  // V epilogue: write transposed to vt[b][d][token] via LDS bounce.
  __syncthreads();
  const int b_ = m0 >> 11;
  const int tok0 = m0 & 2047;
  ushort* vtb = (ushort*)C0 + (size_t)b_ * DIM * SEQ;
  ushort* T = SH;                        // [256 d][132 tok]
  {
#pragma unroll
    for (int nf = 0; nf < 4; ++nf) {
      int d_loc = wn * 64 + nf * 16 + (lane & 15);
      float bvv = x0[n0 + d_loc];
#pragma unroll
      for (int mf = 0; mf < 4; ++mf) {
        int tok = wm * 64 + mf * 16 + (lane >> 4) * 4;
        ushort4 pk;
        pk.x = f2b(acc[mf][nf][0] + bvv);
        pk.y = f2b(acc[mf][nf][1] + bvv);
        pk.z = f2b(acc[mf][nf][2] + bvv);
        pk.w = f2b(acc[mf][nf][3] + bvv);
        *(ushort4*)&T[d_loc * 132 + tok] = pk;
      }
    }
  }
  __syncthreads();
  {
    int rr = t >> 1, ch = t & 1;
    ushort* dst = vtb + (size_t)(n0 + rr) * SEQ + tok0 + ch * 64;
#pragma unroll
    for (int i = 0; i < 8; ++i)
      *(bf16x8*)(dst + i * 8) = *(const bf16x8*)&T[rr * 132 + ch * 64 + i * 8];
  }
}

// ====== FUSED qk + v: 512 blocks; v blocks backfill CUs as qk retires ======
__global__ __launch_bounds__(512) void qkv_fused(
    const ushort* __restrict__ xb, const ushort* __restrict__ wqk,
    void* __restrict__ qb, void* __restrict__ kb,
    const float* __restrict__ bq, const float* __restrict__ bk,
    const ushort* __restrict__ wv, void* __restrict__ vt,
    const float* __restrict__ bv)
{
  __shared__ ushort SH[73728];   // 144 KiB (max of both bodies)
  if (blockIdx.x < 256) {
    gemm256_body<0>(SH, 8, 32, blockIdx.x, 0, xb, wqk, qb, kb, bq, bk,
                    nullptr, DIM, DIM, 1.0f, 0, 0, 0);
  } else {
    gemm_v_body(SH, 4, 64, blockIdx.x - 256, xb, wv, vt, bv);
  }
}

__global__ __launch_bounds__(512) void gemm_s(
    const ushort* __restrict__ Ag, const ushort* __restrict__ Bg,
    void* __restrict__ C0, float* __restrict__ lpartT) {
  __shared__ ushort SH[65536];   // 128 KiB
  gemm256_body<1>(SH, 8, 8, blockIdx.y * 8 + blockIdx.x, blockIdx.z,
                  Ag, Bg, C0, nullptr, nullptr, nullptr, lpartT,
                  SEQ, DIM, 0.03125f, (long)SEQ * DIM, (long)SEQ * DIM,
                  (long)SEQ * SEQ);
}

// ====== PV: 128x128, BK=64, 256 thr (4 waves 2Mx2N), 2 BLOCKS/CU ======
// Round-15 body + block-level rowsum finish from lpartT (t<128 sums 32
// L2-hot scalars once, 1/s cached in LDS).
__global__ __launch_bounds__(256) void gemm_pv(
    const ushort* __restrict__ Ag, const ushort* __restrict__ Bg,
    void* __restrict__ C0, const float* __restrict__ lpartT)
{
  constexpr int TSZ = 128 * 64;
  __shared__ ushort SH[4 * TSZ];           // 64 KiB
  constexpr int N = DIM, Kd = SEQ;

  int nwg = gridDim.x * gridDim.y;
  int id = blockIdx.y * gridDim.x + blockIdx.x;
  int swz = (nwg & 7) ? id : ((id & 7) * (nwg >> 3) + (id >> 3));
  const int m0 = (swz / gridDim.x) * 128;
  const int n0 = (swz % gridDim.x) * 128;
  const int bz = blockIdx.z;
  const char* Ab = (const char*)(Ag + (size_t)bz * (size_t)SEQ * SEQ);
  const char* Bb = (const char*)(Bg + (size_t)bz * (size_t)DIM * SEQ);
  const int t = threadIdx.x;
  const int lane = t & 63;
  const int w = t >> 6;
  const int wm = w >> 1, wn = w & 1;
  const size_t pitch = (size_t)Kd * 2;
  const int nt = Kd >> 6;

  auto stage1 = [&](ushort* ldsb, const char* gb) {
#pragma unroll
    for (int j = 0; j < 4; ++j) {
      int g = j * 256 + t;
      int r = g >> 3;
      int cb = ((g & 7) << 4) ^ ((r & 7) << 4);
      gload_lds16(gb + (size_t)r * pitch + cb,
                  (char*)ldsb + (size_t)((j * 256 + (t & ~63)) << 4));
    }
  };
  auto stageT = [&](int tile) {
    const size_t ko = (size_t)tile * 128;
    stage1(SH + (tile & 1) * TSZ, Ab + (size_t)m0 * pitch + ko);
    stage1(SH + 2 * TSZ + (tile & 1) * TSZ, Bb + (size_t)n0 * pitch + ko);
  };
  auto ldfrag = [&](const ushort* base, int row, int ks) -> bf16x8 {
    int L = row * 128 + ks * 64 + ((lane >> 4) << 4);
    return *(const bf16x8*)((const char*)base + (L ^ ((row & 7) << 4)));
  };

  f32x4 acc[4][4];
#pragma unroll
  for (int i = 0; i < 4; ++i)
#pragma unroll
    for (int j = 0; j < 4; ++j) acc[i][j] = 0.f;

  bf16x8 a[2][2];
  bf16x8 b[4][2];

  stageT(0);

  for (int tt = 0; tt < nt; ++tt) {
    const ushort* Ac = SH + (tt & 1) * TSZ;
    const ushort* Bc = SH + 2 * TSZ + (tt & 1) * TSZ;
    BAR();
    if (tt + 1 < nt) { stageT(tt + 1); VWAIT(8); }
    else VWAIT(0);
    BAR();
#pragma unroll
    for (int nf = 0; nf < 4; ++nf) {
      int r = wn * 64 + nf * 16 + (lane & 15);
      b[nf][0] = ldfrag(Bc, r, 0);
      b[nf][1] = ldfrag(Bc, r, 1);
    }
#pragma unroll
    for (int g = 0; g < 2; ++g) {
#pragma unroll
      for (int i = 0; i < 2; ++i) {
        int r = wm * 64 + (g * 2 + i) * 16 + (lane & 15);
        a[i][0] = ldfrag(Ac, r, 0);
        a[i][1] = ldfrag(Ac, r, 1);
      }
      __builtin_amdgcn_s_setprio(1);
#pragma unroll
      for (int i = 0; i < 2; ++i)
#pragma unroll
        for (int nf = 0; nf < 4; ++nf) {
          acc[g * 2 + i][nf] = MFMA16(b[nf][0], a[i][0], acc[g * 2 + i][nf]);
          acc[g * 2 + i][nf] = MFMA16(b[nf][1], a[i][1], acc[g * 2 + i][nf]);
        }
      __builtin_amdgcn_s_setprio(0);
    }
  }

  // ---- rowsum finish: Linv[128] in LDS from lpartT[b][32][2048] ----
  __syncthreads();                         // all LDS reads done; reuse SH
  float* Lf = (float*)SH;
  if (t < 128) {
    const float* lp = lpartT + (size_t)bz * 32 * SEQ + m0 + t;
    float s = 0.f;
#pragma unroll
    for (int j = 0; j < 32; ++j) s += lp[(size_t)j * SEQ];
    Lf[t] = 1.f / s;
  }
  __syncthreads();

  float* Cf = (float*)C0 + (size_t)bz * (size_t)SEQ * DIM;
#pragma unroll
  for (int mf = 0; mf < 4; ++mf) {
    int rloc = wm * 64 + mf * 16 + (lane & 15);
    int row = m0 + rloc;
    float inv = Lf[rloc];
#pragma unroll
    for (int nf = 0; nf < 4; ++nf) {
      int gn0 = n0 + wn * 64 + nf * 16 + (lane >> 4) * 4;
      f32x4 o = acc[mf][nf] * inv;
      *(f32x4*)&Cf[(size_t)row * DIM + gn0] = o;
    }
  }
}

// ---------------- launcher ----------------
extern "C" void kernel_launch(void* const* d_in, const int* in_sizes, int n_in,
                              void* d_out, int out_size, void* d_ws, size_t ws_size,
                              hipStream_t stream) {
  const float* x  = (const float*)d_in[0];
  const float* Wq = (const float*)d_in[1];
  const float* bq = (const float*)d_in[2];
  const float* Wk = (const float*)d_in[3];
  const float* bk = (const float*)d_in[4];
  const float* Wv = (const float*)d_in[5];
  const float* bv = (const float*)d_in[6];
  float* out = (float*)d_out;

  char* ws = (char*)d_ws;
  // ws layout (bytes), total 90.2 MB:
  //   [0, 32M)      SP  [4][2048][2048] bf16 (xb at [16M,32M) dead by then)
  //   [32M, 38.3M)  wb  (dead after qkv_fused) / lpartT overlay [4][32][2048] f32
  //   [38.3M, ...)  qb | kb | vt  (16M each)
  ushort* xb = (ushort*)(ws + 16777216);
  ushort* wb = (ushort*)(ws + 33554432);
  ushort* qb = (ushort*)(ws + 39845888);
  ushort* kb = (ushort*)(ws + 56623104);
  ushort* vt = (ushort*)(ws + 73400320);
  ushort* SP = (ushort*)(ws);
  float* lpartT = (float*)(ws + 33554432);  // [4][32][2048] f32 = 1 MB

  cvt_all<<<11264, 256, 0, stream>>>(x, Wq, Wk, Wv, xb, wb);
  // Fused: blocks 0-255 = Q,K projection (256x256 tiles);
  //        blocks 256-511 = V projection (128x256 tiles, transposed out).
  qkv_fused<<<512, 512, 0, stream>>>(xb, wb, qb, kb, bq, bk,
                                     wb + 2097152, vt, bv);
  // P = exp(Q K^T / 32) -> SP (+ wave partial sums -> lpartT).  256 blocks.
  gemm_s<<<dim3(8, 8, 4), 512, 0, stream>>>(qb, kb, SP, lpartT);
  // O = (P V) / rowsum.  512 blocks (8x16x4) of 128x128 -> 2 blocks/CU.
  gemm_pv<<<dim3(8, 16, 4), 256, 0, stream>>>(SP, vt, out, lpartT);
}